// Round 3
// baseline (644.771 us; speedup 1.0000x reference)
//
#include <hip/hip_runtime.h>
#include <math.h>

typedef unsigned short u16;
typedef __bf16 bf16x8 __attribute__((ext_vector_type(8)));
typedef float f32x4 __attribute__((ext_vector_type(4)));

typedef __attribute__((address_space(1))) const void gas_t;
typedef __attribute__((address_space(3))) void las_t;

__device__ __forceinline__ void async16(const void* g, void* l) {
    __builtin_amdgcn_global_load_lds((gas_t*)g, (las_t*)l, 16, 0, 0);
}

__device__ __forceinline__ float b2f(u16 u) {
    union { unsigned u; float f; } c; c.u = ((unsigned)u) << 16; return c.f;
}
__device__ __forceinline__ u16 f2b(float f) {
    union { float f; unsigned u; } c; c.f = f;
    unsigned x = c.u + 0x7FFFu + ((c.u >> 16) & 1u);
    return (u16)(x >> 16);
}

// ---------------- f32 -> bf16 conversion ----------------
__global__ __launch_bounds__(256)
void cvt_kernel(const float* __restrict__ in, u16* __restrict__ out, int n4) {
    int i = blockIdx.x * 256 + threadIdx.x;
    int stride = gridDim.x * 256;
    for (; i < n4; i += stride) {
        float4 f = ((const float4*)in)[i];
        ushort4 u;
        u.x = f2b(f.x); u.y = f2b(f.y); u.z = f2b(f.z); u.w = f2b(f.w);
        ((ushort4*)out)[i] = u;
    }
}

// ---------------- rotated phase-weights: wp[bh][p*64+v][d] ----------------
// Fold RoPE into W (adjoint of rotate_half):
//   Wp[v,d] = cos_p[d]*W[v,d] + sin_p[d]*( d<32 ? +W[v,d+32] : -W[v,d-32] )
__global__ __launch_bounds__(256)
void wprep_kernel(const float* __restrict__ W, u16* __restrict__ wp) {
    int idx = blockIdx.x * 256 + threadIdx.x;   // < 64*6*64*64 = 1572864
    int d = idx & 63;
    int v = (idx >> 6) & 63;
    int p = (idx >> 12) % 6;
    int bh = idx / 24576;
    const float* Wb = W + (((size_t)bh * 64 + v) << 6);
    float invf = expf(-(float)(d & 31) * (9.210340371976184f / 32.f)); // 10000^(-(d%32)/32)
    float ang = (float)p * invf;
    float c = cosf(ang), s = sinf(ang);
    float rot = (d < 32) ? Wb[d + 32] : -Wb[d - 32];
    wp[idx] = f2b(c * Wb[d] + s * rot);
}

// ---------------- bf16 GEMM  C = A @ Bw^T  (A: MxK, Bw: NxK, both row-major bf16)
// MODE 0: write bf16 C.  MODE 1: out_f32 = resid + sigmoid(*scale)*C.
template<int MODE>
__global__ __launch_bounds__(256)
void gemm_bt(const u16* __restrict__ A, const u16* __restrict__ Bw,
             int M, int N, int K,
             u16* __restrict__ obf, const float* __restrict__ resid,
             float* __restrict__ of32, const float* __restrict__ scale_ptr) {
    __shared__ __align__(16) u16 lsA[128 * 64];
    __shared__ __align__(16) u16 lsB[128 * 64];
    const int tid = threadIdx.x;
    const int lane = tid & 63;
    const int w = tid >> 6;
    const int nbx = N >> 7;

    // XCD-aware swizzle (gridDim.x % 8 == 0 in all launches)
    int bid = blockIdx.x;
    const int cpx = gridDim.x >> 3;
    bid = (bid & 7) * cpx + (bid >> 3);
    const int m0 = (bid / nbx) << 7;
    const int n0 = (bid % nbx) << 7;

    const int wr = (w >> 1) << 6;
    const int wc = (w & 1) << 6;

    f32x4 acc[4][4];
#pragma unroll
    for (int i = 0; i < 4; ++i)
#pragma unroll
        for (int j = 0; j < 4; ++j) acc[i][j] = (f32x4){0.f, 0.f, 0.f, 0.f};

    const int srow = lane >> 3;                 // row within 8-row chunk
    const int sslot = (lane & 7) ^ srow;        // pre-swizzled 16B slot (G4 XOR swizzle)
    const char* Ab = (const char*)A;
    const char* Bb = (const char*)Bw;
    const int kIters = K >> 6;

    for (int kt = 0; kt < kIters; ++kt) {
        const int k0 = kt << 6;
        __syncthreads();
#pragma unroll
        for (int i = 0; i < 4; ++i) {
            int rowA = m0 + i * 32 + w * 8 + srow;
            async16(Ab + ((size_t)rowA * K + k0) * 2 + (sslot << 4),
                    (char*)lsA + i * 4096 + w * 1024);
            int rowB = n0 + i * 32 + w * 8 + srow;
            async16(Bb + ((size_t)rowB * K + k0) * 2 + (sslot << 4),
                    (char*)lsB + i * 4096 + w * 1024);
        }
        __syncthreads();
#pragma unroll
        for (int kk = 0; kk < 2; ++kk) {
            const int kb = kk * 64 + ((lane >> 4) << 4);
            bf16x8 af[4], bf[4];
#pragma unroll
            for (int m = 0; m < 4; ++m) {
                int row = wr + m * 16 + (lane & 15);
                af[m] = *(const bf16x8*)((const char*)lsA + row * 128 + (kb ^ ((row & 7) << 4)));
            }
#pragma unroll
            for (int n = 0; n < 4; ++n) {
                int row = wc + n * 16 + (lane & 15);
                bf[n] = *(const bf16x8*)((const char*)lsB + row * 128 + (kb ^ ((row & 7) << 4)));
            }
#pragma unroll
            for (int m = 0; m < 4; ++m)
#pragma unroll
                for (int n = 0; n < 4; ++n)
                    acc[m][n] = __builtin_amdgcn_mfma_f32_16x16x32_bf16(af[m], bf[n], acc[m][n], 0, 0, 0);
        }
    }

    float sig = 0.f;
    if (MODE == 1) sig = 1.f / (1.f + expf(-scale_ptr[0]));

    const int crow0 = wr + ((lane >> 4) << 2);
    const int ccol = wc + (lane & 15);
#pragma unroll
    for (int m = 0; m < 4; ++m) {
#pragma unroll
        for (int n = 0; n < 4; ++n) {
#pragma unroll
            for (int r = 0; r < 4; ++r) {
                size_t gi = (size_t)(m0 + crow0 + m * 16 + r) * N + (n0 + ccol + n * 16);
                if (MODE == 0) obf[gi] = f2b(acc[m][n][r]);
                else           of32[gi] = resid[gi] + sig * acc[m][n][r];
            }
        }
    }
}

// ---------------- per-row k scale: scK[b][h][t] = 1/max(||k_row||,1e-12) ----------------
__global__ __launch_bounds__(256)
void knorm_kernel(const u16* __restrict__ kb, float* __restrict__ scK) {
    int t = blockIdx.x * 256 + threadIdx.x;    // 262144 rows: (b*4096+tt)*16 + h
    int h = t & 15;
    size_t row = (size_t)(t >> 4);             // b*4096 + tt
    const uint4* p = (const uint4*)(kb + row * 1024 + h * 64);
    float ss = 0.f;
#pragma unroll
    for (int i = 0; i < 8; ++i) {
        uint4 d = p[i];
        unsigned a[4] = {d.x, d.y, d.z, d.w};
#pragma unroll
        for (int j = 0; j < 4; ++j) {
            union { unsigned u; float f; } lo, hi;
            lo.u = a[j] << 16; hi.u = a[j] & 0xFFFF0000u;
            ss += lo.f * lo.f + hi.f * hi.f;
        }
    }
    float sc = 1.0f / fmaxf(sqrtf(ss), 1e-12f);
    scK[((row >> 12) * 16 + h) * 4096 + (row & 4095)] = sc;
}

// ---------------- fused phase-reads + softmax + merged ----------------
__global__ __launch_bounds__(256)
void reads_kernel(const u16* __restrict__ qb, const u16* __restrict__ wp,
                  u16* __restrict__ merged) {
    __shared__ __align__(16) u16 lsW[384 * 64];   // swizzled
    const int tid = threadIdx.x, lane = tid & 63, w = tid >> 6;
    const int bh = blockIdx.x, tc = blockIdx.y;
    const int b = bh >> 4, h = bh & 15;

    const char* src = (const char*)(wp + (size_t)bh * 24576);
#pragma unroll
    for (int it = 0; it < 12; ++it) {
        int x = (it * 256 + tid) << 4;            // dest byte in LDS (linear)
        int row = x >> 7;
        int wb = x & 127;
        *(uint4*)((char*)lsW + x) = *(const uint4*)(src + row * 128 + (wb ^ ((row & 7) << 4)));
    }
    __syncthreads();

    for (int tt = 0; tt < 4; ++tt) {
        const int t0 = tc * 256 + tt * 64 + w * 16;
        const size_t qoff = ((size_t)b * 4096 + t0 + (lane & 15)) * 1024 + h * 64 + ((lane >> 4) << 3);
        uint4 a0u = *(const uint4*)&qb[qoff];
        uint4 a1u = *(const uint4*)&qb[qoff + 32];

        float ss = 0.f;
        {
            unsigned a[8] = {a0u.x, a0u.y, a0u.z, a0u.w, a1u.x, a1u.y, a1u.z, a1u.w};
#pragma unroll
            for (int i = 0; i < 8; ++i) {
                union { unsigned u; float f; } lo, hi;
                lo.u = a[i] << 16; hi.u = a[i] & 0xFFFF0000u;
                ss += lo.f * lo.f + hi.f * hi.f;
            }
        }
        ss += __shfl_xor(ss, 16);
        ss += __shfl_xor(ss, 32);
        float sc = 1.0f / fmaxf(sqrtf(ss), 1e-12f);
        float rsc[4];
#pragma unroll
        for (int r = 0; r < 4; ++r) rsc[r] = __shfl(sc, ((lane >> 4) << 2) + r);

        bf16x8 a0 = __builtin_bit_cast(bf16x8, a0u);
        bf16x8 a1 = __builtin_bit_cast(bf16x8, a1u);

        f32x4 acc[24];
#pragma unroll
        for (int i = 0; i < 24; ++i) acc[i] = (f32x4){0.f, 0.f, 0.f, 0.f};
#pragma unroll
        for (int kk = 0; kk < 2; ++kk) {
            bf16x8 a = kk ? a1 : a0;
            const int kb = kk * 64 + ((lane >> 4) << 4);
#pragma unroll
            for (int nf = 0; nf < 24; ++nf) {
                int row = nf * 16 + (lane & 15);
                bf16x8 bb = *(const bf16x8*)((const char*)lsW + row * 128 + (kb ^ ((row & 7) << 4)));
                acc[nf] = __builtin_amdgcn_mfma_f32_16x16x32_bf16(a, bb, acc[nf], 0, 0, 0);
            }
        }

        // scores -> softmax over 6 phases (per C-row)
        float alpha[6][4];
#pragma unroll
        for (int p = 0; p < 6; ++p) {
            float ps[4] = {0.f, 0.f, 0.f, 0.f};
#pragma unroll
            for (int fv = 0; fv < 4; ++fv) {
                f32x4 v = acc[p * 4 + fv];
#pragma unroll
                for (int r = 0; r < 4; ++r) ps[r] += v[r] * v[r];
            }
#pragma unroll
            for (int r = 0; r < 4; ++r) {
                float x = ps[r];
                x += __shfl_xor(x, 1);
                x += __shfl_xor(x, 2);
                x += __shfl_xor(x, 4);
                x += __shfl_xor(x, 8);
                alpha[p][r] = sqrtf(x) * rsc[r] * (5.0f / 8.0f);  // TEMP/sqrt(DV)
            }
        }
#pragma unroll
        for (int r = 0; r < 4; ++r) {
            float m = alpha[0][r];
#pragma unroll
            for (int p = 1; p < 6; ++p) m = fmaxf(m, alpha[p][r]);
            float s = 0.f;
#pragma unroll
            for (int p = 0; p < 6; ++p) { float e = expf(alpha[p][r] - m); s += e; alpha[p][r] = e; }
            float inv = 1.f / s;
#pragma unroll
            for (int p = 0; p < 6; ++p) alpha[p][r] *= inv;
        }
#pragma unroll
        for (int fv = 0; fv < 4; ++fv) {
#pragma unroll
            for (int r = 0; r < 4; ++r) {
                float o = 0.f;
#pragma unroll
                for (int p = 0; p < 6; ++p) o += alpha[p][r] * acc[p * 4 + fv][r];
                o *= rsc[r];
                size_t gi = ((size_t)b * 4096 + t0 + ((lane >> 4) << 2) + r) * 1024
                            + h * 64 + fv * 16 + (lane & 15);
                merged[gi] = f2b(o);
            }
        }
    }
}

// ---------------- residual partial outer products (deterministic, no atomics) -------
__global__ __launch_bounds__(256)
void resid_kernel(const u16* __restrict__ kb, const u16* __restrict__ vb,
                  const float* __restrict__ scK, float* __restrict__ part) {
    const int bh = blockIdx.x, sp = blockIdx.y;
    const int b = bh >> 4, h = bh & 15;
    const int tid = threadIdx.x;
    const int dg = tid >> 6, v = tid & 63;
    float acc[16];
#pragma unroll
    for (int j = 0; j < 16; ++j) acc[j] = 0.f;
    const int t0 = sp * 256;
    for (int t = 0; t < 256; ++t) {
        size_t row = ((size_t)b * 4096 + t0 + t) * 1024 + h * 64;
        float vvs = b2f(vb[row + v]) * scK[(size_t)bh * 4096 + t0 + t];
        uint4 k0 = *(const uint4*)&kb[row + dg * 16];
        uint4 k1 = *(const uint4*)&kb[row + dg * 16 + 8];
        unsigned ka[8] = {k0.x, k0.y, k0.z, k0.w, k1.x, k1.y, k1.z, k1.w};
#pragma unroll
        for (int i = 0; i < 8; ++i) {
            union { unsigned u; float f; } lo, hi;
            lo.u = ka[i] << 16; hi.u = ka[i] & 0xFFFF0000u;
            acc[2 * i]     = fmaf(vvs, lo.f, acc[2 * i]);
            acc[2 * i + 1] = fmaf(vvs, hi.f, acc[2 * i + 1]);
        }
    }
    float* dst = part + ((size_t)sp * 64 + bh) * 4096 + v * 64 + dg * 16;
#pragma unroll
    for (int i = 0; i < 4; ++i) {
        float4 f4; f4.x = acc[4 * i]; f4.y = acc[4 * i + 1]; f4.z = acc[4 * i + 2]; f4.w = acc[4 * i + 3];
        *(float4*)(dst + i * 4) = f4;
    }
}

// ---------------- W_new = 0.9*aged + sum(part)/T ----------------
__global__ __launch_bounds__(256)
void wnew_kernel(const float* __restrict__ W, const float* __restrict__ part,
                 float* __restrict__ outW) {
    int idx = blockIdx.x * 256 + threadIdx.x;   // 262144
    int d = idx & 63;
    float w = W[idx];
    float rot = (d < 32) ? -W[idx + 32] : W[idx - 32];
    float invf = expf(-(float)(d & 31) * (9.210340371976184f / 32.f));
    float aged = w * cosf(invf) + rot * sinf(invf);
    float r = 0.f;
#pragma unroll
    for (int s = 0; s < 16; ++s) r += part[(size_t)s * 262144 + idx];
    outW[idx] = 0.9f * aged + r * (1.0f / 4096.0f);
}

extern "C" void kernel_launch(void* const* d_in, const int* in_sizes, int n_in,
                              void* d_out, int out_size, void* d_ws, size_t ws_size,
                              hipStream_t stream) {
    const float* hidden = (const float*)d_in[0];
    const float* Wturn  = (const float*)d_in[1];
    const float* qw     = (const float*)d_in[2];
    const float* ow     = (const float*)d_in[3];
    const float* kw     = (const float*)d_in[4];
    const float* vw     = (const float*)d_in[5];
    const float* rs     = (const float*)d_in[6];
    float* out  = (float*)d_out;
    float* outW = out + 33554432;

    char* ws = (char*)d_ws;
    u16* hid_bf = (u16*)(ws + 0);             // 33.5M el (67,108,864 B)
    u16* q_bf   = (u16*)(ws + 67108864);      // 16.8M el
    u16* k_bf   = (u16*)(ws + 100663296);
    u16* v_bf   = (u16*)(ws + 134217728);
    u16* mrg    = (u16*)(ws + 167772160);
    u16* qw_bf  = (u16*)(ws + 201326592);     // 2.1M el
    u16* kw_bf  = (u16*)(ws + 205520896);
    u16* vw_bf  = (u16*)(ws + 209715200);
    u16* ow_bf  = (u16*)(ws + 213909504);
    u16* wp     = (u16*)(ws + 218103808);     // 1.57M el
    float* scK  = (float*)(ws + 221249536);   // 262144 el
    float* part = (float*)(ws + 222298112);   // 16*262144 el  (end ~239 MB)

    cvt_kernel<<<4096, 256, 0, stream>>>(hidden, hid_bf, 33554432 / 4);
    cvt_kernel<<<2048, 256, 0, stream>>>(qw, qw_bf, 2097152 / 4);
    cvt_kernel<<<2048, 256, 0, stream>>>(kw, kw_bf, 2097152 / 4);
    cvt_kernel<<<2048, 256, 0, stream>>>(vw, vw_bf, 2097152 / 4);
    cvt_kernel<<<2048, 256, 0, stream>>>(ow, ow_bf, 2097152 / 4);
    wprep_kernel<<<6144, 256, 0, stream>>>(Wturn, wp);

    gemm_bt<0><<<1024, 256, 0, stream>>>(hid_bf, qw_bf, 16384, 1024, 2048, q_bf, nullptr, nullptr, nullptr);
    gemm_bt<0><<<1024, 256, 0, stream>>>(hid_bf, kw_bf, 16384, 1024, 2048, k_bf, nullptr, nullptr, nullptr);
    gemm_bt<0><<<1024, 256, 0, stream>>>(hid_bf, vw_bf, 16384, 1024, 2048, v_bf, nullptr, nullptr, nullptr);

    knorm_kernel<<<1024, 256, 0, stream>>>(k_bf, scK);
    reads_kernel<<<dim3(64, 16), 256, 0, stream>>>(q_bf, wp, mrg);
    gemm_bt<1><<<2048, 256, 0, stream>>>(mrg, ow_bf, 16384, 2048, 1024, nullptr, hidden, out, rs);
    resid_kernel<<<dim3(64, 16), 256, 0, stream>>>(k_bf, v_bf, scK, part);
    wnew_kernel<<<1024, 256, 0, stream>>>(Wturn, part, outW);
}

// Round 4
// 589.666 us; speedup vs baseline: 1.0935x; 1.0935x over previous
//
#include <hip/hip_runtime.h>
#include <math.h>

typedef unsigned short u16;
typedef __bf16 bf16x8 __attribute__((ext_vector_type(8)));
typedef float f32x4 __attribute__((ext_vector_type(4)));

typedef __attribute__((address_space(1))) const void gas_t;
typedef __attribute__((address_space(3))) void las_t;

__device__ __forceinline__ void async16(const void* g, void* l) {
    __builtin_amdgcn_global_load_lds((gas_t*)g, (las_t*)l, 16, 0, 0);
}

__device__ __forceinline__ float b2f(u16 u) {
    union { unsigned u; float f; } c; c.u = ((unsigned)u) << 16; return c.f;
}
__device__ __forceinline__ u16 f2b(float f) {
    union { float f; unsigned u; } c; c.f = f;
    unsigned x = c.u + 0x7FFFu + ((c.u >> 16) & 1u);
    return (u16)(x >> 16);
}

// ---------------- f32 -> bf16 conversion ----------------
__global__ __launch_bounds__(256)
void cvt_kernel(const float* __restrict__ in, u16* __restrict__ out, int n4) {
    int i = blockIdx.x * 256 + threadIdx.x;
    int stride = gridDim.x * 256;
    for (; i < n4; i += stride) {
        float4 f = ((const float4*)in)[i];
        ushort4 u;
        u.x = f2b(f.x); u.y = f2b(f.y); u.z = f2b(f.z); u.w = f2b(f.w);
        ((ushort4*)out)[i] = u;
    }
}

// ---------------- rotated phase-weights: wp[bh][p*64+v][d] ----------------
// Fold RoPE into W (adjoint of rotate_half):
//   Wp[v,d] = cos_p[d]*W[v,d] + sin_p[d]*( d<32 ? +W[v,d+32] : -W[v,d-32] )
__global__ __launch_bounds__(256)
void wprep_kernel(const float* __restrict__ W, u16* __restrict__ wp) {
    int idx = blockIdx.x * 256 + threadIdx.x;   // < 64*6*64*64 = 1572864
    int d = idx & 63;
    int v = (idx >> 6) & 63;
    int p = (idx >> 12) % 6;
    int bh = idx / 24576;
    const float* Wb = W + (((size_t)bh * 64 + v) << 6);
    float invf = expf(-(float)(d & 31) * (9.210340371976184f / 32.f)); // 10000^(-(d%32)/32)
    float ang = (float)p * invf;
    float c = cosf(ang), s = sinf(ang);
    float rot = (d < 32) ? Wb[d + 32] : -Wb[d - 32];
    wp[idx] = f2b(c * Wb[d] + s * rot);
}

// ---------------- bf16 GEMM  C = A @ Bw^T  (A: MxK, Bw: NxK, both row-major bf16)
// MODE 0: write bf16 C.  MODE 1: out_f32 = resid + sigmoid(*scale)*C.
// MFMA operands SWAPPED (mfma(bf, af)): reg quad spans the N (contiguous)
// axis -> vectorized epilogue: ushort4 (MODE 0) / float4 (MODE 1) per frag.
template<int MODE>
__global__ __launch_bounds__(256)
void gemm_bt(const u16* __restrict__ A, const u16* __restrict__ Bw,
             int M, int N, int K,
             u16* __restrict__ obf, const float* __restrict__ resid,
             float* __restrict__ of32, const float* __restrict__ scale_ptr) {
    __shared__ __align__(16) u16 lsA[128 * 64];
    __shared__ __align__(16) u16 lsB[128 * 64];
    const int tid = threadIdx.x;
    const int lane = tid & 63;
    const int w = tid >> 6;
    const int nbx = N >> 7;

    // XCD-aware swizzle (gridDim.x % 8 == 0 in all launches)
    int bid = blockIdx.x;
    const int cpx = gridDim.x >> 3;
    bid = (bid & 7) * cpx + (bid >> 3);
    const int m0 = (bid / nbx) << 7;
    const int n0 = (bid % nbx) << 7;

    const int wr = (w >> 1) << 6;
    const int wc = (w & 1) << 6;

    f32x4 acc[4][4];
#pragma unroll
    for (int i = 0; i < 4; ++i)
#pragma unroll
        for (int j = 0; j < 4; ++j) acc[i][j] = (f32x4){0.f, 0.f, 0.f, 0.f};

    const int srow = lane >> 3;                 // row within 8-row chunk
    const int sslot = (lane & 7) ^ srow;        // pre-swizzled 16B slot (G4 XOR swizzle)
    const char* Ab = (const char*)A;
    const char* Bb = (const char*)Bw;
    const int kIters = K >> 6;

    for (int kt = 0; kt < kIters; ++kt) {
        const int k0 = kt << 6;
        __syncthreads();
#pragma unroll
        for (int i = 0; i < 4; ++i) {
            int rowA = m0 + i * 32 + w * 8 + srow;
            async16(Ab + ((size_t)rowA * K + k0) * 2 + (sslot << 4),
                    (char*)lsA + i * 4096 + w * 1024);
            int rowB = n0 + i * 32 + w * 8 + srow;
            async16(Bb + ((size_t)rowB * K + k0) * 2 + (sslot << 4),
                    (char*)lsB + i * 4096 + w * 1024);
        }
        __syncthreads();
#pragma unroll
        for (int kk = 0; kk < 2; ++kk) {
            const int kb = kk * 64 + ((lane >> 4) << 4);
            bf16x8 af[4], bf[4];
#pragma unroll
            for (int m = 0; m < 4; ++m) {
                int row = wr + m * 16 + (lane & 15);
                af[m] = *(const bf16x8*)((const char*)lsA + row * 128 + (kb ^ ((row & 7) << 4)));
            }
#pragma unroll
            for (int n = 0; n < 4; ++n) {
                int row = wc + n * 16 + (lane & 15);
                bf[n] = *(const bf16x8*)((const char*)lsB + row * 128 + (kb ^ ((row & 7) << 4)));
            }
#pragma unroll
            for (int m = 0; m < 4; ++m)
#pragma unroll
                for (int n = 0; n < 4; ++n)
                    acc[m][n] = __builtin_amdgcn_mfma_f32_16x16x32_bf16(bf[n], af[m], acc[m][n], 0, 0, 0);
        }
    }

    float sig = 0.f;
    if (MODE == 1) sig = 1.f / (1.f + expf(-scale_ptr[0]));

    // Swapped C/D layout: M-row = lane&15 (+m*16), N-col = (lane>>4)*4 + r (+n*16)
    const int crow = wr + (lane & 15);
    const int ccol0 = wc + ((lane >> 4) << 2);
#pragma unroll
    for (int m = 0; m < 4; ++m) {
#pragma unroll
        for (int n = 0; n < 4; ++n) {
            size_t gi = (size_t)(m0 + crow + m * 16) * N + (n0 + ccol0 + n * 16);
            if (MODE == 0) {
                ushort4 u;
                u.x = f2b(acc[m][n][0]); u.y = f2b(acc[m][n][1]);
                u.z = f2b(acc[m][n][2]); u.w = f2b(acc[m][n][3]);
                *(ushort4*)&obf[gi] = u;
            } else {
                float4 rv = *(const float4*)&resid[gi];
                float4 o;
                o.x = rv.x + sig * acc[m][n][0];
                o.y = rv.y + sig * acc[m][n][1];
                o.z = rv.z + sig * acc[m][n][2];
                o.w = rv.w + sig * acc[m][n][3];
                *(float4*)&of32[gi] = o;
            }
        }
    }
}

// ---------------- per-row k scale: scK[b][h][t] = 1/max(||k_row||,1e-12) ----------------
__global__ __launch_bounds__(256)
void knorm_kernel(const u16* __restrict__ kb, float* __restrict__ scK) {
    int t = blockIdx.x * 256 + threadIdx.x;    // 262144 rows: (b*4096+tt)*16 + h
    int h = t & 15;
    size_t row = (size_t)(t >> 4);             // b*4096 + tt
    const uint4* p = (const uint4*)(kb + row * 1024 + h * 64);
    float ss = 0.f;
#pragma unroll
    for (int i = 0; i < 8; ++i) {
        uint4 d = p[i];
        unsigned a[4] = {d.x, d.y, d.z, d.w};
#pragma unroll
        for (int j = 0; j < 4; ++j) {
            union { unsigned u; float f; } lo, hi;
            lo.u = a[j] << 16; hi.u = a[j] & 0xFFFF0000u;
            ss += lo.f * lo.f + hi.f * hi.f;
        }
    }
    float sc = 1.0f / fmaxf(sqrtf(ss), 1e-12f);
    scK[((row >> 12) * 16 + h) * 4096 + (row & 4095)] = sc;
}

// ---------------- fused phase-reads + softmax + merged ----------------
// Swapped MFMA (mfma(W, q)): t-row = lane&15 (sc lane-local, softmax scalar),
// v-col = (lane>>4)*4 + r -> ushort4 merged stores.
__global__ __launch_bounds__(256)
void reads_kernel(const u16* __restrict__ qb, const u16* __restrict__ wp,
                  u16* __restrict__ merged) {
    __shared__ __align__(16) u16 lsW[384 * 64];   // swizzled
    const int tid = threadIdx.x, lane = tid & 63, w = tid >> 6;
    const int bh = blockIdx.x, tc = blockIdx.y;
    const int b = bh >> 4, h = bh & 15;

    const char* src = (const char*)(wp + (size_t)bh * 24576);
#pragma unroll
    for (int it = 0; it < 12; ++it) {
        int x = (it * 256 + tid) << 4;            // dest byte in LDS (linear)
        int row = x >> 7;
        int wb = x & 127;
        *(uint4*)((char*)lsW + x) = *(const uint4*)(src + row * 128 + (wb ^ ((row & 7) << 4)));
    }
    __syncthreads();

    for (int tt = 0; tt < 4; ++tt) {
        const int t0 = tc * 256 + tt * 64 + w * 16;
        const size_t qoff = ((size_t)b * 4096 + t0 + (lane & 15)) * 1024 + h * 64 + ((lane >> 4) << 3);
        uint4 a0u = *(const uint4*)&qb[qoff];
        uint4 a1u = *(const uint4*)&qb[qoff + 32];

        float ss = 0.f;
        {
            unsigned a[8] = {a0u.x, a0u.y, a0u.z, a0u.w, a1u.x, a1u.y, a1u.z, a1u.w};
#pragma unroll
            for (int i = 0; i < 8; ++i) {
                union { unsigned u; float f; } lo, hi;
                lo.u = a[i] << 16; hi.u = a[i] & 0xFFFF0000u;
                ss += lo.f * lo.f + hi.f * hi.f;
            }
        }
        ss += __shfl_xor(ss, 16);
        ss += __shfl_xor(ss, 32);
        float sc = 1.0f / fmaxf(sqrtf(ss), 1e-12f);   // lane-local: this lane's t-row

        bf16x8 a0 = __builtin_bit_cast(bf16x8, a0u);
        bf16x8 a1 = __builtin_bit_cast(bf16x8, a1u);

        f32x4 acc[24];
#pragma unroll
        for (int i = 0; i < 24; ++i) acc[i] = (f32x4){0.f, 0.f, 0.f, 0.f};
#pragma unroll
        for (int kk = 0; kk < 2; ++kk) {
            bf16x8 a = kk ? a1 : a0;
            const int kb = kk * 64 + ((lane >> 4) << 4);
#pragma unroll
            for (int nf = 0; nf < 24; ++nf) {
                int row = nf * 16 + (lane & 15);
                bf16x8 bb = *(const bf16x8*)((const char*)lsW + row * 128 + (kb ^ ((row & 7) << 4)));
                acc[nf] = __builtin_amdgcn_mfma_f32_16x16x32_bf16(bb, a, acc[nf], 0, 0, 0);
            }
        }

        // scores -> softmax over 6 phases (scalar per lane; lane owns t-row = lane&15)
        float alpha[6];
#pragma unroll
        for (int p = 0; p < 6; ++p) {
            float x = 0.f;
#pragma unroll
            for (int fv = 0; fv < 4; ++fv) {
                f32x4 v = acc[p * 4 + fv];
#pragma unroll
                for (int r = 0; r < 4; ++r) x += v[r] * v[r];
            }
            // full ||read||^2: reduce across the 4 lane-groups (v-col quads)
            x += __shfl_xor(x, 16);
            x += __shfl_xor(x, 32);
            alpha[p] = sqrtf(x) * sc * (5.0f / 8.0f);  // TEMP/sqrt(DV)
        }
        {
            float m = alpha[0];
#pragma unroll
            for (int p = 1; p < 6; ++p) m = fmaxf(m, alpha[p]);
            float s = 0.f;
#pragma unroll
            for (int p = 0; p < 6; ++p) { float e = expf(alpha[p] - m); s += e; alpha[p] = e; }
            float inv = 1.f / s;
#pragma unroll
            for (int p = 0; p < 6; ++p) alpha[p] *= inv;
        }
#pragma unroll
        for (int fv = 0; fv < 4; ++fv) {
            float o[4];
#pragma unroll
            for (int r = 0; r < 4; ++r) {
                float acc_o = 0.f;
#pragma unroll
                for (int p = 0; p < 6; ++p) acc_o += alpha[p] * acc[p * 4 + fv][r];
                o[r] = acc_o * sc;
            }
            size_t gi = ((size_t)b * 4096 + t0 + (lane & 15)) * 1024
                        + h * 64 + fv * 16 + ((lane >> 4) << 2);
            ushort4 u;
            u.x = f2b(o[0]); u.y = f2b(o[1]); u.z = f2b(o[2]); u.w = f2b(o[3]);
            *(ushort4*)&merged[gi] = u;
        }
    }
}

// ---------------- residual partial outer products (deterministic, no atomics) -------
__global__ __launch_bounds__(256)
void resid_kernel(const u16* __restrict__ kb, const u16* __restrict__ vb,
                  const float* __restrict__ scK, float* __restrict__ part) {
    const int bh = blockIdx.x, sp = blockIdx.y;
    const int b = bh >> 4, h = bh & 15;
    const int tid = threadIdx.x;
    const int dg = tid >> 6, v = tid & 63;
    float acc[16];
#pragma unroll
    for (int j = 0; j < 16; ++j) acc[j] = 0.f;
    const int t0 = sp * 256;
    for (int t = 0; t < 256; ++t) {
        size_t row = ((size_t)b * 4096 + t0 + t) * 1024 + h * 64;
        float vvs = b2f(vb[row + v]) * scK[(size_t)bh * 4096 + t0 + t];
        uint4 k0 = *(const uint4*)&kb[row + dg * 16];
        uint4 k1 = *(const uint4*)&kb[row + dg * 16 + 8];
        unsigned ka[8] = {k0.x, k0.y, k0.z, k0.w, k1.x, k1.y, k1.z, k1.w};
#pragma unroll
        for (int i = 0; i < 8; ++i) {
            union { unsigned u; float f; } lo, hi;
            lo.u = ka[i] << 16; hi.u = ka[i] & 0xFFFF0000u;
            acc[2 * i]     = fmaf(vvs, lo.f, acc[2 * i]);
            acc[2 * i + 1] = fmaf(vvs, hi.f, acc[2 * i + 1]);
        }
    }
    float* dst = part + ((size_t)sp * 64 + bh) * 4096 + v * 64 + dg * 16;
#pragma unroll
    for (int i = 0; i < 4; ++i) {
        float4 f4; f4.x = acc[4 * i]; f4.y = acc[4 * i + 1]; f4.z = acc[4 * i + 2]; f4.w = acc[4 * i + 3];
        *(float4*)(dst + i * 4) = f4;
    }
}

// ---------------- W_new = 0.9*aged + sum(part)/T ----------------
__global__ __launch_bounds__(256)
void wnew_kernel(const float* __restrict__ W, const float* __restrict__ part,
                 float* __restrict__ outW) {
    int idx = blockIdx.x * 256 + threadIdx.x;   // 262144
    int d = idx & 63;
    float w = W[idx];
    float rot = (d < 32) ? -W[idx + 32] : W[idx - 32];
    float invf = expf(-(float)(d & 31) * (9.210340371976184f / 32.f));
    float aged = w * cosf(invf) + rot * sinf(invf);
    float r = 0.f;
#pragma unroll
    for (int s = 0; s < 16; ++s) r += part[(size_t)s * 262144 + idx];
    outW[idx] = 0.9f * aged + r * (1.0f / 4096.0f);
}

extern "C" void kernel_launch(void* const* d_in, const int* in_sizes, int n_in,
                              void* d_out, int out_size, void* d_ws, size_t ws_size,
                              hipStream_t stream) {
    const float* hidden = (const float*)d_in[0];
    const float* Wturn  = (const float*)d_in[1];
    const float* qw     = (const float*)d_in[2];
    const float* ow     = (const float*)d_in[3];
    const float* kw     = (const float*)d_in[4];
    const float* vw     = (const float*)d_in[5];
    const float* rs     = (const float*)d_in[6];
    float* out  = (float*)d_out;
    float* outW = out + 33554432;

    char* ws = (char*)d_ws;
    u16* hid_bf = (u16*)(ws + 0);             // 33.5M el (67,108,864 B)
    u16* q_bf   = (u16*)(ws + 67108864);      // 16.8M el
    u16* k_bf   = (u16*)(ws + 100663296);
    u16* v_bf   = (u16*)(ws + 134217728);
    u16* mrg    = (u16*)(ws + 167772160);
    u16* qw_bf  = (u16*)(ws + 201326592);     // 2.1M el
    u16* kw_bf  = (u16*)(ws + 205520896);
    u16* vw_bf  = (u16*)(ws + 209715200);
    u16* ow_bf  = (u16*)(ws + 213909504);
    u16* wp     = (u16*)(ws + 218103808);     // 1.57M el
    float* scK  = (float*)(ws + 221249536);   // 262144 el
    float* part = (float*)(ws + 222298112);   // 16*262144 el  (end ~239 MB)

    cvt_kernel<<<4096, 256, 0, stream>>>(hidden, hid_bf, 33554432 / 4);
    cvt_kernel<<<2048, 256, 0, stream>>>(qw, qw_bf, 2097152 / 4);
    cvt_kernel<<<2048, 256, 0, stream>>>(kw, kw_bf, 2097152 / 4);
    cvt_kernel<<<2048, 256, 0, stream>>>(vw, vw_bf, 2097152 / 4);
    cvt_kernel<<<2048, 256, 0, stream>>>(ow, ow_bf, 2097152 / 4);
    wprep_kernel<<<6144, 256, 0, stream>>>(Wturn, wp);

    gemm_bt<0><<<1024, 256, 0, stream>>>(hid_bf, qw_bf, 16384, 1024, 2048, q_bf, nullptr, nullptr, nullptr);
    gemm_bt<0><<<1024, 256, 0, stream>>>(hid_bf, kw_bf, 16384, 1024, 2048, k_bf, nullptr, nullptr, nullptr);
    gemm_bt<0><<<1024, 256, 0, stream>>>(hid_bf, vw_bf, 16384, 1024, 2048, v_bf, nullptr, nullptr, nullptr);

    knorm_kernel<<<1024, 256, 0, stream>>>(k_bf, scK);
    reads_kernel<<<dim3(64, 16), 256, 0, stream>>>(q_bf, wp, mrg);
    gemm_bt<1><<<2048, 256, 0, stream>>>(mrg, ow_bf, 16384, 2048, 1024, nullptr, hidden, out, rs);
    resid_kernel<<<dim3(64, 16), 256, 0, stream>>>(k_bf, v_bf, scK, part);
    wnew_kernel<<<1024, 256, 0, stream>>>(Wturn, part, outW);
}

// Round 5
// 563.174 us; speedup vs baseline: 1.1449x; 1.0470x over previous
//
#include <hip/hip_runtime.h>
#include <math.h>

typedef unsigned short u16;
typedef __bf16 bf16x8 __attribute__((ext_vector_type(8)));
typedef float f32x4 __attribute__((ext_vector_type(4)));

typedef __attribute__((address_space(1))) const void gas_t;
typedef __attribute__((address_space(3))) void las_t;

__device__ __forceinline__ void async16(const void* g, void* l) {
    __builtin_amdgcn_global_load_lds((gas_t*)g, (las_t*)l, 16, 0, 0);
}

__device__ __forceinline__ float b2f(u16 u) {
    union { unsigned u; float f; } c; c.u = ((unsigned)u) << 16; return c.f;
}
__device__ __forceinline__ u16 f2b(float f) {
    union { float f; unsigned u; } c; c.f = f;
    unsigned x = c.u + 0x7FFFu + ((c.u >> 16) & 1u);
    return (u16)(x >> 16);
}

// ---------------- f32 -> bf16 conversion ----------------
__global__ __launch_bounds__(256)
void cvt_kernel(const float* __restrict__ in, u16* __restrict__ out, int n4) {
    int i = blockIdx.x * 256 + threadIdx.x;
    int stride = gridDim.x * 256;
    for (; i < n4; i += stride) {
        float4 f = ((const float4*)in)[i];
        ushort4 u;
        u.x = f2b(f.x); u.y = f2b(f.y); u.z = f2b(f.z); u.w = f2b(f.w);
        ((ushort4*)out)[i] = u;
    }
}

// ---------------- rotated phase-weights: wp[bh][p*64+v][d] ----------------
// Fold RoPE into W (adjoint of rotate_half):
//   Wp[v,d] = cos_p[d]*W[v,d] + sin_p[d]*( d<32 ? +W[v,d+32] : -W[v,d-32] )
__global__ __launch_bounds__(256)
void wprep_kernel(const float* __restrict__ W, u16* __restrict__ wp) {
    int idx = blockIdx.x * 256 + threadIdx.x;   // < 64*6*64*64 = 1572864
    int d = idx & 63;
    int v = (idx >> 6) & 63;
    int p = (idx >> 12) % 6;
    int bh = idx / 24576;
    const float* Wb = W + (((size_t)bh * 64 + v) << 6);
    float invf = expf(-(float)(d & 31) * (9.210340371976184f / 32.f)); // 10000^(-(d%32)/32)
    float ang = (float)p * invf;
    float c = cosf(ang), s = sinf(ang);
    float rot = (d < 32) ? Wb[d + 32] : -Wb[d - 32];
    wp[idx] = f2b(c * Wb[d] + s * rot);
}

// ---------------- 256^2-tile bf16 GEMM  C = A @ Bw^T, double-buffered pipeline
// A: MxK, Bw: NxK, row-major bf16. 512 threads = 8 waves (2M x 4N), BK=64.
// LDS 128 KiB (2 dbuf x (A+B) x 256x64). One __syncthreads per K-tile:
// STAGE(next) issued BEFORE compute(cur); barrier = vmcnt(0)+lgkmcnt(0) drain.
// MODE 0: write bf16 C.  MODE 1: out_f32 = resid + sigmoid(*scale)*C.
template<int MODE>
__global__ __launch_bounds__(512, 2)
void gemm_bt256(const u16* __restrict__ A, const u16* __restrict__ Bw,
                int M, int N, int K,
                u16* __restrict__ obf, const float* __restrict__ resid,
                float* __restrict__ of32, const float* __restrict__ scale_ptr) {
    __shared__ __align__(16) u16 lsA[2][256 * 64];
    __shared__ __align__(16) u16 lsB[2][256 * 64];
    const int tid = threadIdx.x;
    const int lane = tid & 63;
    const int wm = (tid >> 6) >> 2;   // 0..1
    const int wn = (tid >> 6) & 3;    // 0..3
    const int nbx = N >> 8;

    // XCD-aware swizzle (gridDim.x % 8 == 0 in all launches)
    int bid = blockIdx.x;
    const int cpx = gridDim.x >> 3;
    bid = (bid & 7) * cpx + (bid >> 3);
    const int m0 = (bid / nbx) << 8;
    const int n0 = (bid % nbx) << 8;

    f32x4 acc[8][4];
#pragma unroll
    for (int i = 0; i < 8; ++i)
#pragma unroll
        for (int j = 0; j < 4; ++j) acc[i][j] = (f32x4){0.f, 0.f, 0.f, 0.f};

    const int srow = tid >> 3;                  // 0..63: row within 64-row chunk
    const int sslot = (tid & 7) ^ (srow & 7);   // pre-swizzled global 16B slot
    const char* Ab = (const char*)A;
    const char* Bb = (const char*)Bw;
    const int nkt = K >> 6;

    auto stage = [&](int buf, int kt) {
        const int k0 = kt << 6;
#pragma unroll
        for (int i = 0; i < 4; ++i) {
            int rowA = m0 + i * 64 + srow;
            async16(Ab + ((size_t)rowA * K + k0) * 2 + (sslot << 4),
                    (char*)&lsA[buf][0] + i * 8192 + tid * 16);
            int rowB = n0 + i * 64 + srow;
            async16(Bb + ((size_t)rowB * K + k0) * 2 + (sslot << 4),
                    (char*)&lsB[buf][0] + i * 8192 + tid * 16);
        }
    };

    stage(0, 0);
    __syncthreads();
    int cur = 0;
    for (int kt = 0; kt < nkt; ++kt) {
        if (kt + 1 < nkt) stage(cur ^ 1, kt + 1);   // prefetch overlaps compute
#pragma unroll
        for (int kk = 0; kk < 2; ++kk) {
            const int kb = kk * 64 + ((lane >> 4) << 4);
            bf16x8 af[8], bf[4];
#pragma unroll
            for (int m = 0; m < 8; ++m) {
                int row = wm * 128 + m * 16 + (lane & 15);
                af[m] = *(const bf16x8*)((const char*)&lsA[cur][0] + row * 128 + (kb ^ ((row & 7) << 4)));
            }
#pragma unroll
            for (int n = 0; n < 4; ++n) {
                int row = wn * 64 + n * 16 + (lane & 15);
                bf[n] = *(const bf16x8*)((const char*)&lsB[cur][0] + row * 128 + (kb ^ ((row & 7) << 4)));
            }
            __builtin_amdgcn_s_setprio(1);
#pragma unroll
            for (int m = 0; m < 8; ++m)
#pragma unroll
                for (int n = 0; n < 4; ++n)
                    acc[m][n] = __builtin_amdgcn_mfma_f32_16x16x32_bf16(bf[n], af[m], acc[m][n], 0, 0, 0);
            __builtin_amdgcn_s_setprio(0);
        }
        __syncthreads();   // drains stage loads (vmcnt) + this wave's ds_reads (lgkm)
        cur ^= 1;
    }

    float sig = 0.f;
    if (MODE == 1) sig = 1.f / (1.f + expf(-scale_ptr[0]));

    // Swapped C/D layout: M-row = lane&15 (+m*16), N-col = (lane>>4)*4 + r (+n*16)
    const int crow = wm * 128 + (lane & 15);
    const int ccol0 = wn * 64 + ((lane >> 4) << 2);
#pragma unroll
    for (int m = 0; m < 8; ++m) {
#pragma unroll
        for (int n = 0; n < 4; ++n) {
            size_t gi = (size_t)(m0 + crow + m * 16) * N + (n0 + ccol0 + n * 16);
            if (MODE == 0) {
                ushort4 u;
                u.x = f2b(acc[m][n][0]); u.y = f2b(acc[m][n][1]);
                u.z = f2b(acc[m][n][2]); u.w = f2b(acc[m][n][3]);
                *(ushort4*)&obf[gi] = u;
            } else {
                float4 rv = *(const float4*)&resid[gi];
                float4 o;
                o.x = rv.x + sig * acc[m][n][0];
                o.y = rv.y + sig * acc[m][n][1];
                o.z = rv.z + sig * acc[m][n][2];
                o.w = rv.w + sig * acc[m][n][3];
                *(float4*)&of32[gi] = o;
            }
        }
    }
}

// ---------------- per-row k scale (qkv fused layout: row stride 3072, k at +1024) ----
__global__ __launch_bounds__(256)
void knorm_kernel(const u16* __restrict__ qkv, float* __restrict__ scK) {
    int t = blockIdx.x * 256 + threadIdx.x;    // 262144 rows: (b*4096+tt)*16 + h
    int h = t & 15;
    size_t row = (size_t)(t >> 4);             // b*4096 + tt
    const uint4* p = (const uint4*)(qkv + row * 3072 + 1024 + h * 64);
    float ss = 0.f;
#pragma unroll
    for (int i = 0; i < 8; ++i) {
        uint4 d = p[i];
        unsigned a[4] = {d.x, d.y, d.z, d.w};
#pragma unroll
        for (int j = 0; j < 4; ++j) {
            union { unsigned u; float f; } lo, hi;
            lo.u = a[j] << 16; hi.u = a[j] & 0xFFFF0000u;
            ss += lo.f * lo.f + hi.f * hi.f;
        }
    }
    float sc = 1.0f / fmaxf(sqrtf(ss), 1e-12f);
    scK[((row >> 12) * 16 + h) * 4096 + (row & 4095)] = sc;
}

// ---------------- fused phase-reads + softmax + merged (q from qkv, stride 3072) ----
__global__ __launch_bounds__(256)
void reads_kernel(const u16* __restrict__ qkv, const u16* __restrict__ wp,
                  u16* __restrict__ merged) {
    __shared__ __align__(16) u16 lsW[384 * 64];   // swizzled
    const int tid = threadIdx.x, lane = tid & 63, w = tid >> 6;
    const int bh = blockIdx.x, tc = blockIdx.y;
    const int b = bh >> 4, h = bh & 15;

    const char* src = (const char*)(wp + (size_t)bh * 24576);
#pragma unroll
    for (int it = 0; it < 12; ++it) {
        int x = (it * 256 + tid) << 4;            // dest byte in LDS (linear)
        int row = x >> 7;
        int wb = x & 127;
        *(uint4*)((char*)lsW + x) = *(const uint4*)(src + row * 128 + (wb ^ ((row & 7) << 4)));
    }
    __syncthreads();

    for (int tt = 0; tt < 4; ++tt) {
        const int t0 = tc * 256 + tt * 64 + w * 16;
        const size_t qoff = ((size_t)b * 4096 + t0 + (lane & 15)) * 3072 + h * 64 + ((lane >> 4) << 3);
        uint4 a0u = *(const uint4*)&qkv[qoff];
        uint4 a1u = *(const uint4*)&qkv[qoff + 32];

        float ss = 0.f;
        {
            unsigned a[8] = {a0u.x, a0u.y, a0u.z, a0u.w, a1u.x, a1u.y, a1u.z, a1u.w};
#pragma unroll
            for (int i = 0; i < 8; ++i) {
                union { unsigned u; float f; } lo, hi;
                lo.u = a[i] << 16; hi.u = a[i] & 0xFFFF0000u;
                ss += lo.f * lo.f + hi.f * hi.f;
            }
        }
        ss += __shfl_xor(ss, 16);
        ss += __shfl_xor(ss, 32);
        float sc = 1.0f / fmaxf(sqrtf(ss), 1e-12f);   // lane-local: this lane's t-row

        bf16x8 a0 = __builtin_bit_cast(bf16x8, a0u);
        bf16x8 a1 = __builtin_bit_cast(bf16x8, a1u);

        f32x4 acc[24];
#pragma unroll
        for (int i = 0; i < 24; ++i) acc[i] = (f32x4){0.f, 0.f, 0.f, 0.f};
#pragma unroll
        for (int kk = 0; kk < 2; ++kk) {
            bf16x8 a = kk ? a1 : a0;
            const int kb = kk * 64 + ((lane >> 4) << 4);
#pragma unroll
            for (int nf = 0; nf < 24; ++nf) {
                int row = nf * 16 + (lane & 15);
                bf16x8 bb = *(const bf16x8*)((const char*)lsW + row * 128 + (kb ^ ((row & 7) << 4)));
                acc[nf] = __builtin_amdgcn_mfma_f32_16x16x32_bf16(bb, a, acc[nf], 0, 0, 0);
            }
        }

        // scores -> softmax over 6 phases (scalar per lane; lane owns t-row = lane&15)
        float alpha[6];
#pragma unroll
        for (int p = 0; p < 6; ++p) {
            float x = 0.f;
#pragma unroll
            for (int fv = 0; fv < 4; ++fv) {
                f32x4 v = acc[p * 4 + fv];
#pragma unroll
                for (int r = 0; r < 4; ++r) x += v[r] * v[r];
            }
            x += __shfl_xor(x, 16);
            x += __shfl_xor(x, 32);
            alpha[p] = sqrtf(x) * sc * (5.0f / 8.0f);  // TEMP/sqrt(DV)
        }
        {
            float m = alpha[0];
#pragma unroll
            for (int p = 1; p < 6; ++p) m = fmaxf(m, alpha[p]);
            float s = 0.f;
#pragma unroll
            for (int p = 0; p < 6; ++p) { float e = expf(alpha[p] - m); s += e; alpha[p] = e; }
            float inv = 1.f / s;
#pragma unroll
            for (int p = 0; p < 6; ++p) alpha[p] *= inv;
        }
#pragma unroll
        for (int fv = 0; fv < 4; ++fv) {
            float o[4];
#pragma unroll
            for (int r = 0; r < 4; ++r) {
                float acc_o = 0.f;
#pragma unroll
                for (int p = 0; p < 6; ++p) acc_o += alpha[p] * acc[p * 4 + fv][r];
                o[r] = acc_o * sc;
            }
            size_t gi = ((size_t)b * 4096 + t0 + (lane & 15)) * 1024
                        + h * 64 + fv * 16 + ((lane >> 4) << 2);
            ushort4 u;
            u.x = f2b(o[0]); u.y = f2b(o[1]); u.z = f2b(o[2]); u.w = f2b(o[3]);
            *(ushort4*)&merged[gi] = u;
        }
    }
}

// ---------------- residual partial outer products (k,v from fused qkv) -------
__global__ __launch_bounds__(256)
void resid_kernel(const u16* __restrict__ qkv,
                  const float* __restrict__ scK, float* __restrict__ part) {
    const int bh = blockIdx.x, sp = blockIdx.y;
    const int b = bh >> 4, h = bh & 15;
    const int tid = threadIdx.x;
    const int dg = tid >> 6, v = tid & 63;
    float acc[16];
#pragma unroll
    for (int j = 0; j < 16; ++j) acc[j] = 0.f;
    const int t0 = sp * 256;
    for (int t = 0; t < 256; ++t) {
        size_t row = ((size_t)b * 4096 + t0 + t) * 3072 + h * 64;
        float vvs = b2f(qkv[row + 2048 + v]) * scK[(size_t)bh * 4096 + t0 + t];
        uint4 k0 = *(const uint4*)&qkv[row + 1024 + dg * 16];
        uint4 k1 = *(const uint4*)&qkv[row + 1024 + dg * 16 + 8];
        unsigned ka[8] = {k0.x, k0.y, k0.z, k0.w, k1.x, k1.y, k1.z, k1.w};
#pragma unroll
        for (int i = 0; i < 8; ++i) {
            union { unsigned u; float f; } lo, hi;
            lo.u = ka[i] << 16; hi.u = ka[i] & 0xFFFF0000u;
            acc[2 * i]     = fmaf(vvs, lo.f, acc[2 * i]);
            acc[2 * i + 1] = fmaf(vvs, hi.f, acc[2 * i + 1]);
        }
    }
    float* dst = part + ((size_t)sp * 64 + bh) * 4096 + v * 64 + dg * 16;
#pragma unroll
    for (int i = 0; i < 4; ++i) {
        float4 f4; f4.x = acc[4 * i]; f4.y = acc[4 * i + 1]; f4.z = acc[4 * i + 2]; f4.w = acc[4 * i + 3];
        *(float4*)(dst + i * 4) = f4;
    }
}

// ---------------- W_new = 0.9*aged + sum(part)/T ----------------
__global__ __launch_bounds__(256)
void wnew_kernel(const float* __restrict__ W, const float* __restrict__ part,
                 float* __restrict__ outW) {
    int idx = blockIdx.x * 256 + threadIdx.x;   // 262144
    int d = idx & 63;
    float w = W[idx];
    float rot = (d < 32) ? -W[idx + 32] : W[idx - 32];
    float invf = expf(-(float)(d & 31) * (9.210340371976184f / 32.f));
    float aged = w * cosf(invf) + rot * sinf(invf);
    float r = 0.f;
#pragma unroll
    for (int s = 0; s < 16; ++s) r += part[(size_t)s * 262144 + idx];
    outW[idx] = 0.9f * aged + r * (1.0f / 4096.0f);
}

extern "C" void kernel_launch(void* const* d_in, const int* in_sizes, int n_in,
                              void* d_out, int out_size, void* d_ws, size_t ws_size,
                              hipStream_t stream) {
    const float* hidden = (const float*)d_in[0];
    const float* Wturn  = (const float*)d_in[1];
    const float* qw     = (const float*)d_in[2];
    const float* ow     = (const float*)d_in[3];
    const float* kw     = (const float*)d_in[4];
    const float* vw     = (const float*)d_in[5];
    const float* rs     = (const float*)d_in[6];
    float* out  = (float*)d_out;
    float* outW = out + 33554432;

    char* ws = (char*)d_ws;
    u16* hid_bf = (u16*)(ws + 0);             // 16384x2048 bf16 (67,108,864 B)
    u16* qkv    = (u16*)(ws + 67108864);      // 16384x3072 bf16 (100,663,296 B)
    u16* mrg    = (u16*)(ws + 167772160);     // 16384x1024 bf16 (33,554,432 B)
    u16* wcat   = (u16*)(ws + 201326592);     // 3072x2048 bf16 (12,582,912 B): q|k|v
    u16* ow_bf  = (u16*)(ws + 213909504);     // 2048x1024 bf16 (4,194,304 B)
    u16* wp     = (u16*)(ws + 218103808);     // 64x384x64 bf16 (3,145,728 B)
    float* scK  = (float*)(ws + 221249536);   // 262144 f32
    float* part = (float*)(ws + 222298112);   // 16x262144 f32 (end ~239 MB)

    cvt_kernel<<<4096, 256, 0, stream>>>(hidden, hid_bf, 33554432 / 4);
    cvt_kernel<<<2048, 256, 0, stream>>>(qw, wcat,           2097152 / 4);
    cvt_kernel<<<2048, 256, 0, stream>>>(kw, wcat + 2097152, 2097152 / 4);
    cvt_kernel<<<2048, 256, 0, stream>>>(vw, wcat + 4194304, 2097152 / 4);
    cvt_kernel<<<2048, 256, 0, stream>>>(ow, ow_bf, 2097152 / 4);
    wprep_kernel<<<6144, 256, 0, stream>>>(Wturn, wp);

    // fused q|k|v projection: (16384x2048) @ (3072x2048)^T -> qkv
    gemm_bt256<0><<<768, 512, 0, stream>>>(hid_bf, wcat, 16384, 3072, 2048, qkv, nullptr, nullptr, nullptr);

    knorm_kernel<<<1024, 256, 0, stream>>>(qkv, scK);
    reads_kernel<<<dim3(64, 16), 256, 0, stream>>>(qkv, wp, mrg);
    gemm_bt256<1><<<512, 512, 0, stream>>>(mrg, ow_bf, 16384, 2048, 1024, nullptr, hidden, out, rs);
    resid_kernel<<<dim3(64, 16), 256, 0, stream>>>(qkv, scK, part);
    wnew_kernel<<<1024, 256, 0, stream>>>(Wturn, part, outW);
}